// Round 7
// baseline (158.198 us; speedup 1.0000x reference)
//
#include <hip/hip_runtime.h>

typedef unsigned short u16;
typedef _Float16 f16x8 __attribute__((ext_vector_type(8)));
typedef __fp16 hf16x2 __attribute__((ext_vector_type(2)));
typedef float f32x4 __attribute__((ext_vector_type(4)));
typedef float f32x16 __attribute__((ext_vector_type(16)));
typedef unsigned uint2v __attribute__((ext_vector_type(2)));

#define NB 8
#define NC 512
#define NHD 8
#define DH 64
#define NN 1024
#define LOG2E 1.4426950408889634f

__device__ __forceinline__ u16 f2h(float f) {
    union { _Float16 h; u16 u; } v; v.h = (_Float16)f;
    return v.u;
}

// ================= kernel 1: fused prep =================
// blocks [0,2048): transpose x/d [b,c,n] -> [b,n,c] fp16
// blocks [2048,2816): convert Wq/Wk/Wv fp32 -> fp16 (float4 vectorized)
// blocks [2816,4864): pos[h,i,d] = rel_h + rel_w fp16
__global__ __launch_bounds__(256) void k_prep(
    const float* __restrict__ x, const float* __restrict__ d,
    const float* __restrict__ Wq, const float* __restrict__ Wk, const float* __restrict__ Wv,
    const float* __restrict__ relh, const float* __restrict__ relw,
    u16* __restrict__ xt, u16* __restrict__ dt,
    u16* __restrict__ wq, u16* __restrict__ wk, u16* __restrict__ wv,
    u16* __restrict__ ps) {
    __shared__ float tile[64][65];
    int id = blockIdx.x, t = threadIdx.x;
    if (id < 2048) {
        // ---- transpose+cvt ----
        int nb = (id & 15) * 64;
        int cb = ((id >> 4) & 7) * 64;
        int z = id >> 7;
        int b = z & 7;
        const float* src = (z >> 3) ? d : x;
        u16* ot = (z >> 3) ? dt : xt;
        {
            int crow = t >> 2, n0 = (t & 3) * 16;
            const float* g = src + ((size_t)(b * NC + cb + crow)) * NN + nb + n0;
#pragma unroll
            for (int k = 0; k < 16; k += 4) {
                float4 v = *(const float4*)(g + k);
                tile[crow][n0 + k + 0] = v.x;
                tile[crow][n0 + k + 1] = v.y;
                tile[crow][n0 + k + 2] = v.z;
                tile[crow][n0 + k + 3] = v.w;
            }
        }
        __syncthreads();
        {
            int nrow = t >> 2, c0 = (t & 3) * 16;
            union { u16 s[16]; uint4 v[2]; } uh;
#pragma unroll
            for (int k = 0; k < 16; ++k) uh.s[k] = f2h(tile[c0 + k][nrow]);
            size_t oidx = ((size_t)(b * NN + nb + nrow)) * NC + cb + c0;
            *(uint4*)(ot + oidx)     = uh.v[0];
            *(uint4*)(ot + oidx + 8) = uh.v[1];
        }
    } else if (id < 2816) {
        int j = id - 2048;            // 0..767
        int m = j >> 8;               // tensor select
        int blk = j & 255;
        const float* src = (m == 0) ? Wq : (m == 1) ? Wk : Wv;
        u16* dst = (m == 0) ? wq : (m == 1) ? wk : wv;
        int i = (blk * 256 + t) * 4;
        float4 v = *(const float4*)(src + i);
        union { u16 s[4]; uint2 u2; } r;
        r.s[0] = f2h(v.x); r.s[1] = f2h(v.y); r.s[2] = f2h(v.z); r.s[3] = f2h(v.w);
        *(uint2*)(dst + i) = r.u2;
    } else {
        int idx = (id - 2816) * 256 + t;
        int dd = idx & 63;
        int i  = (idx >> 6) & 1023;
        int h  = idx >> 16;
        float f = relh[(h * 64 + dd) * 32 + (i & 31)] + relw[(h * 64 + dd) * 32 + (i >> 5)];
        ps[(h * 1024 + i) * 64 + dd] = f2h(f);
    }
}

// ================= kernel 2: projection GEMM, fp16, 2-phase DMA pipeline =================
// Double-buffered global_load_lds staging, ONE barrier per K-step: stage(k+1)
// issued BEFORE compute(k). This kernel is 8-wave LOCKSTEP (no second block's
// compute to hide the drain under), so prefetch genuinely helps here
// (round-5: ~-13us) -- unlike k_attn where cross-block TLP already hides it.
// q output is PRE-SCALED by log2(e) (softmax runs in exp2 domain).
__global__ __launch_bounds__(256) void k_proj(
    const u16* __restrict__ xt, const u16* __restrict__ dt,
    const u16* __restrict__ wq, const u16* __restrict__ wk, const u16* __restrict__ wv,
    const float* __restrict__ bq, const float* __restrict__ bk, const float* __restrict__ bv,
    u16* __restrict__ qt_o, u16* __restrict__ kt_o, u16* __restrict__ v_o) {
    __shared__ u16 Asm[2][128 * 32];   // UNPADDED: required by global_load_lds lane mapping
    __shared__ u16 Bsm[2][128 * 32];

    int p = blockIdx.z % 3;
    int b = blockIdx.z / 3;
    const u16 *Ap, *Bp;
    const float* bias;
    u16* Oq;
    if (p == 0)      { Ap = wq; Bp = xt; bias = bq; Oq = qt_o; }
    else if (p == 1) { Ap = wk; Bp = dt; bias = bk; Oq = kt_o; }
    else             { Ap = wv; Bp = dt; bias = bv; Oq = v_o; }
    Bp += (size_t)b * NN * NC;
    float oscale = (p == 0) ? LOG2E : 1.0f;

    int obase = blockIdx.x * 128;
    int nbase = blockIdx.y * 128;
    int t = threadIdx.x, wave = t >> 6, quad = (t & 63) >> 4, l15 = t & 15;
    int wr = (wave >> 1) * 64, wc = (wave & 1) * 64;

    f32x4 acc[4][4];
#pragma unroll
    for (int fo = 0; fo < 4; ++fo)
#pragma unroll
        for (int fn = 0; fn < 4; ++fn)
#pragma unroll
            for (int r = 0; r < 4; ++r) acc[fo][fn][r] = 0.f;

    auto stage = [&](int kk, int buf) {
#pragma unroll
        for (int u = 0; u < 2; ++u) {
            int c = u * 256 + t;
            int row = c >> 2, part = c & 3;
            __builtin_amdgcn_global_load_lds(
                (const __attribute__((address_space(1))) void*)(Ap + (size_t)(obase + row) * NC + kk + part * 8),
                (__attribute__((address_space(3))) void*)(&Asm[buf][0] + (size_t)(u * 256 + wave * 64) * 8), 16, 0, 0);
            __builtin_amdgcn_global_load_lds(
                (const __attribute__((address_space(1))) void*)(Bp + (size_t)(nbase + row) * NC + kk + part * 8),
                (__attribute__((address_space(3))) void*)(&Bsm[buf][0] + (size_t)(u * 256 + wave * 64) * 8), 16, 0, 0);
        }
    };

    stage(0, 0);
    __syncthreads();                 // vmcnt(0) drain + publish buf0

    for (int kk = 0; kk < NC; kk += 32) {
        int cur = (kk >> 5) & 1;
        if (kk + 32 < NC) stage(kk + 32, cur ^ 1);   // prefetch next K-step

        f16x8 af[4], bfr[4];
#pragma unroll
        for (int fo = 0; fo < 4; ++fo) af[fo] = *(const f16x8*)&Asm[cur][(wr + fo * 16 + l15) * 32 + quad * 8];
#pragma unroll
        for (int fn = 0; fn < 4; ++fn) bfr[fn] = *(const f16x8*)&Bsm[cur][(wc + fn * 16 + l15) * 32 + quad * 8];
#pragma unroll
        for (int fo = 0; fo < 4; ++fo)
#pragma unroll
            for (int fn = 0; fn < 4; ++fn)
                acc[fo][fn] = __builtin_amdgcn_mfma_f32_16x16x32_f16(af[fo], bfr[fn], acc[fo][fn], 0, 0, 0);

        __syncthreads();             // drains prefetch DMA (hidden by MFMAs) + guards overwrite
    }

#pragma unroll
    for (int fo = 0; fo < 4; ++fo) {
#pragma unroll
        for (int fn = 0; fn < 4; ++fn) {
            int o0 = obase + wr + fo * 16 + quad * 4;     // 4-aligned, never crosses a head
            int n = nbase + wc + fn * 16 + l15;
            if (p < 2) {
                union { u16 s[4]; uint2 v2; } uh;
#pragma unroll
                for (int r = 0; r < 4; ++r) uh.s[r] = f2h((acc[fo][fn][r] + bias[o0 + r]) * oscale);
                int head = o0 >> 6, dd0 = o0 & 63;
                size_t idx = (((size_t)(b * NHD + head) * NN) + n) * DH + dd0;
                *(uint2*)&Oq[idx] = uh.v2;
            } else {
#pragma unroll
                for (int r = 0; r < 4; ++r) {
                    int o = o0 + r;
                    int head = o >> 6, dd = o & 63;
                    Oq[((size_t)(b * NHD + head) * DH + dd) * NN + n] = f2h(acc[fo][fn][r] + bias[o]);
                }
            }
        }
    }
}

// ================= kernel 3: fused flash attention v6 (REVERTED) =================
// Round-6 lesson: BOTH pipelined variants (v7 KVBLK=64 2-phase, v8 Vt-dbuf
// cross-phase) measured ~47us vs v6's <=41us. With 2 blocks/CU at staggered
// phases, cross-block TLP already hides the staging drain (m114); splitting
// the stage costs VGPR (88->124), LDS (48->64K), and puts DMA LDS-writes in
// contention with compute-phase ds_reads. v6's dedicated stage phase is the
// measured optimum for this decomposition. Staging via global_load_lds DMA,
// XOR chunk swizzle (inverse-swizzled global source, linear LDS dest),
// in-register P transpose (permlane32_swap), defer-max (T13), setprio (T5).
__global__ __launch_bounds__(256, 2) void k_attn(
    const u16* __restrict__ qt, const u16* __restrict__ kt,
    const u16* __restrict__ v_, const u16* __restrict__ pos,
    float* __restrict__ out) {
    __shared__ u16 Bs[128 * 128];      // rows j: chunks 0-7 = K[j], 8-15 = Q[j] (swizzled)
    __shared__ u16 Vt[64 * 128];       // [d][j 128] (swizzled)

    // XCD swizzle: all 8 i-blocks of group g=(b,head) land on XCD g%8
    int n = blockIdx.x;
    int g = n & 63;
    int ib = n >> 6;
    int head = g & 7, b = g >> 3;

    int t = threadIdx.x, ws = t >> 6, lane = t & 63, h = lane >> 5, l31 = lane & 31;
    size_t bh = (size_t)(b * NHD + head);
    const u16* qb = qt + bh * NN * DH;
    const u16* kb = kt + bh * NN * DH;
    const u16* vb = v_ + bh * DH * NN;
    const u16* pb = pos + (size_t)head * NN * DH;
    int i0 = ib * 128;
    int iglob = i0 + ws * 32 + l31;

    // wave-private B-operand frags: k 0..63 = q_i (pre-scaled by log2e), 64..127 = pos_i
    f16x8 qf[8];
#pragma unroll
    for (int ks = 0; ks < 4; ++ks) qf[ks] = *(const f16x8*)&qb[(size_t)iglob * DH + ks * 16 + h * 8];
#pragma unroll
    for (int ks = 4; ks < 8; ++ks) qf[ks] = *(const f16x8*)&pb[(size_t)iglob * DH + (ks - 4) * 16 + h * 8];

    f32x16 oacc[2];
#pragma unroll
    for (int df = 0; df < 2; ++df)
#pragma unroll
        for (int r = 0; r < 16; ++r) oacc[df][r] = 0.f;
    float m_ = -__builtin_inff(), l_ = 0.f;
    int swz = l31 & 7;                 // read-side XOR key (row & 7)

    for (int jc = 0; jc < NN; jc += 128) {
        __syncthreads();
        // ---- stage Bs via DMA: 2048 chunks of 16B; lane's LDS slot is linear,
        // source chunk is XOR-permuted so LDS[row][p] holds logical chunk p^(row&7)
#pragma unroll
        for (int u = 0; u < 8; ++u) {
            int c = u * 256 + t;
            int row = c >> 4, c16 = c & 15;
            int gch = c16 ^ (row & 7);
            const u16* src = (gch < 8) ? &kb[(size_t)(jc + row) * DH + gch * 8]
                                       : &qb[(size_t)(jc + row) * DH + (gch - 8) * 8];
            __builtin_amdgcn_global_load_lds(
                (const __attribute__((address_space(1))) void*)src,
                (__attribute__((address_space(3))) void*)(Bs + (u * 256 + ws * 64) * 8), 16, 0, 0);
        }
        // ---- stage Vt via DMA: 1024 chunks
#pragma unroll
        for (int u = 0; u < 4; ++u) {
            int c = u * 256 + t;
            int row = c >> 4, c16 = c & 15;
            int gch = c16 ^ (row & 7);
            __builtin_amdgcn_global_load_lds(
                (const __attribute__((address_space(1))) void*)&vb[(size_t)row * NN + jc + gch * 8],
                (__attribute__((address_space(3))) void*)(Vt + (u * 256 + ws * 64) * 8), 16, 0, 0);
        }
        __syncthreads();

        // ---- S^T: 4 j-frags of 32 rows, extended K=128 over 8 ks ----
        f32x16 sacc[4];
#pragma unroll
        for (int jf = 0; jf < 4; ++jf)
#pragma unroll
            for (int r = 0; r < 16; ++r) sacc[jf][r] = 0.f;
        __builtin_amdgcn_s_setprio(1);
#pragma unroll
        for (int jf = 0; jf < 4; ++jf)
#pragma unroll
            for (int ks = 0; ks < 8; ++ks) {
                f16x8 af = *(const f16x8*)&Bs[(jf * 32 + l31) * 128 + ((ks * 2 + h) ^ swz) * 8];
                sacc[jf] = __builtin_amdgcn_mfma_f32_32x32x16_f16(af, qf[ks], sacc[jf], 0, 0, 0);
            }
        __builtin_amdgcn_s_setprio(0);

        // ---- online softmax over 128 j (exp2 domain; S pre-scaled by log2e) ----
        float mj[4];
#pragma unroll
        for (int jf = 0; jf < 4; ++jf) {
            float a = fmaxf(fmaxf(sacc[jf][0], sacc[jf][1]), sacc[jf][2]);
            a = fmaxf(fmaxf(a, sacc[jf][3]), sacc[jf][4]);
            a = fmaxf(fmaxf(a, sacc[jf][5]), sacc[jf][6]);
            a = fmaxf(fmaxf(a, sacc[jf][7]), sacc[jf][8]);
            a = fmaxf(fmaxf(a, sacc[jf][9]), sacc[jf][10]);
            a = fmaxf(fmaxf(a, sacc[jf][11]), sacc[jf][12]);
            a = fmaxf(fmaxf(a, sacc[jf][13]), sacc[jf][14]);
            mj[jf] = fmaxf(a, sacc[jf][15]);
        }
        float mloc = fmaxf(fmaxf(mj[0], mj[1]), fmaxf(mj[2], mj[3]));
        mloc = fmaxf(mloc, __shfl_xor(mloc, 32));
        // defer-max (T13): rescale only when running max grew by >8 (exp2
        // domain => P bounded by 2^8=256, safely inside fp16; fp32 accum).
        if (__any(mloc - m_ > 8.f)) {
            float mnew = fmaxf(m_, mloc);
            float alpha = __builtin_amdgcn_exp2f(m_ - mnew);
            m_ = mnew;
#pragma unroll
            for (int df = 0; df < 2; ++df)
#pragma unroll
                for (int r = 0; r < 16; ++r) oacc[df][r] *= alpha;
            l_ *= alpha;
        }
        float ls[4];
#pragma unroll
        for (int jf = 0; jf < 4; ++jf) {
            float s = 0.f;
#pragma unroll
            for (int r = 0; r < 16; ++r) {
                float pv = __builtin_amdgcn_exp2f(sacc[jf][r] - m_);
                sacc[jf][r] = pv;
                s += pv;
            }
            ls[jf] = s;
        }
        float lsum = (ls[0] + ls[1]) + (ls[2] + ls[3]);
        lsum += __shfl_xor(lsum, 32);
        l_ += lsum;

        // ---- P -> B-operand fragments fully in-register + PV ----
        // Lane(h,l31) holds sacc[jf][r] = P[j5=(r&3)+8*(r>>2)+4h][i=l31]. PV
        // B-frag for slice jw needs pf[e] = P[jw*16 + h*8 + e][l31]. With
        // r0=(jw&1)*8: h=0 needs {own a0,a1 | h=1's a0,a1}; h=1 needs
        // {h=0's b0,b1 | own b0,b1}. permlane32_swap(a,b) -> {w0, w2}.
        __builtin_amdgcn_s_setprio(1);
#pragma unroll
        for (int jw = 0; jw < 8; ++jw) {
            int jf = jw >> 1, r0 = (jw & 1) * 8;
            union { hf16x2 v; unsigned u; } a0, a1, b0, b1;
            a0.v = __builtin_amdgcn_cvt_pkrtz(sacc[jf][r0 + 0], sacc[jf][r0 + 1]);
            a1.v = __builtin_amdgcn_cvt_pkrtz(sacc[jf][r0 + 2], sacc[jf][r0 + 3]);
            b0.v = __builtin_amdgcn_cvt_pkrtz(sacc[jf][r0 + 4], sacc[jf][r0 + 5]);
            b1.v = __builtin_amdgcn_cvt_pkrtz(sacc[jf][r0 + 6], sacc[jf][r0 + 7]);
            uint2v s0 = __builtin_amdgcn_permlane32_swap(a0.u, b0.u, false, false);
            uint2v s1 = __builtin_amdgcn_permlane32_swap(a1.u, b1.u, false, false);
            union { unsigned w[4]; f16x8 f; } pf;
            pf.w[0] = s0.x;
            pf.w[1] = s1.x;
            pf.w[2] = s0.y;
            pf.w[3] = s1.y;
#pragma unroll
            for (int df = 0; df < 2; ++df) {
                f16x8 vf = *(const f16x8*)&Vt[(df * 32 + l31) * 128 + ((jw * 2 + h) ^ swz) * 8];
                oacc[df] = __builtin_amdgcn_mfma_f32_32x32x16_f16(vf, pf.f, oacc[df], 0, 0, 0);
            }
        }
        __builtin_amdgcn_s_setprio(0);
    }

    // ---- epilogue ----
    float li = 1.0f / l_;
#pragma unroll
    for (int df = 0; df < 2; ++df)
#pragma unroll
        for (int r = 0; r < 16; ++r) {
            int dd = df * 32 + (r & 3) + 8 * (r >> 2) + 4 * h;
            out[((size_t)(b * NC) + head * DH + dd) * NN + i0 + ws * 32 + l31] = oacc[df][r] * li;
        }
}

// ================= workspace layout (bytes) =================
#define SXT  (8u * 1024u * 512u * 2u)      /* 8 MB: [B,N,C] fp16 */
#define SW   (512u * 512u * 2u)
#define SQT  SXT
#define SPOS (8u * 1024u * 64u * 2u)

#define OFF_XT   (0u)
#define OFF_DT   (OFF_XT + SXT)
#define OFF_WQ   (OFF_DT + SXT)
#define OFF_WK   (OFF_WQ + SW)
#define OFF_WV   (OFF_WK + SW)
#define OFF_QT   (OFF_WV + SW)
#define OFF_KT   (OFF_QT + SQT)
#define OFF_V    (OFF_KT + SQT)
#define OFF_POS  (OFF_V + SQT)
// total = 5*8388608 + 3*524288 + 1048576 = 44,564,480 bytes (~42.5 MiB)

extern "C" void kernel_launch(void* const* d_in, const int* in_sizes, int n_in,
                              void* d_out, int out_size, void* d_ws, size_t ws_size,
                              hipStream_t stream) {
    const float* x   = (const float*)d_in[0];
    const float* d   = (const float*)d_in[1];
    const float* Wq  = (const float*)d_in[2];
    const float* bq  = (const float*)d_in[3];
    const float* Wk  = (const float*)d_in[4];
    const float* bk  = (const float*)d_in[5];
    const float* Wv  = (const float*)d_in[6];
    const float* bv  = (const float*)d_in[7];
    const float* rh  = (const float*)d_in[8];
    const float* rw  = (const float*)d_in[9];

    char* ws = (char*)d_ws;
    u16* xt = (u16*)(ws + OFF_XT);
    u16* dt = (u16*)(ws + OFF_DT);
    u16* wq = (u16*)(ws + OFF_WQ);
    u16* wk = (u16*)(ws + OFF_WK);
    u16* wv = (u16*)(ws + OFF_WV);
    u16* qt = (u16*)(ws + OFF_QT);
    u16* kt = (u16*)(ws + OFF_KT);
    u16* v_ = (u16*)(ws + OFF_V);
    u16* ps = (u16*)(ws + OFF_POS);

    k_prep<<<4864, 256, 0, stream>>>(x, d, Wq, Wk, Wv, rh, rw, xt, dt, wq, wk, wv, ps);
    k_proj<<<dim3(4, 8, 24), 256, 0, stream>>>(xt, dt, wq, wk, wv, bq, bk, bv, qt, kt, v_);
    k_attn<<<512, 256, 0, stream>>>(qt, kt, v_, ps, (float*)d_out);
}

// Round 8
// 155.218 us; speedup vs baseline: 1.0192x; 1.0192x over previous
//
#include <hip/hip_runtime.h>

typedef unsigned short u16;
typedef _Float16 f16x8 __attribute__((ext_vector_type(8)));
typedef __fp16 hf16x2 __attribute__((ext_vector_type(2)));
typedef float f32x4 __attribute__((ext_vector_type(4)));
typedef float f32x16 __attribute__((ext_vector_type(16)));
typedef unsigned uint2v __attribute__((ext_vector_type(2)));

#define NB 8
#define NC 512
#define NHD 8
#define DH 64
#define NN 1024
#define LOG2E 1.4426950408889634f

__device__ __forceinline__ u16 f2h(float f) {
    union { _Float16 h; u16 u; } v; v.h = (_Float16)f;
    return v.u;
}

// ================= kernel 1: fused prep =================
// blocks [0,2048): transpose x/d [b,c,n] -> [b,n,c] fp16
// blocks [2048,2816): convert Wq/Wk/Wv fp32 -> fp16 (float4 vectorized)
// blocks [2816,4864): pos[h,i,d] = rel_h + rel_w fp16
__global__ __launch_bounds__(256) void k_prep(
    const float* __restrict__ x, const float* __restrict__ d,
    const float* __restrict__ Wq, const float* __restrict__ Wk, const float* __restrict__ Wv,
    const float* __restrict__ relh, const float* __restrict__ relw,
    u16* __restrict__ xt, u16* __restrict__ dt,
    u16* __restrict__ wq, u16* __restrict__ wk, u16* __restrict__ wv,
    u16* __restrict__ ps) {
    __shared__ float tile[64][65];
    int id = blockIdx.x, t = threadIdx.x;
    if (id < 2048) {
        // ---- transpose+cvt ----
        int nb = (id & 15) * 64;
        int cb = ((id >> 4) & 7) * 64;
        int z = id >> 7;
        int b = z & 7;
        const float* src = (z >> 3) ? d : x;
        u16* ot = (z >> 3) ? dt : xt;
        {
            int crow = t >> 2, n0 = (t & 3) * 16;
            const float* g = src + ((size_t)(b * NC + cb + crow)) * NN + nb + n0;
#pragma unroll
            for (int k = 0; k < 16; k += 4) {
                float4 v = *(const float4*)(g + k);
                tile[crow][n0 + k + 0] = v.x;
                tile[crow][n0 + k + 1] = v.y;
                tile[crow][n0 + k + 2] = v.z;
                tile[crow][n0 + k + 3] = v.w;
            }
        }
        __syncthreads();
        {
            int nrow = t >> 2, c0 = (t & 3) * 16;
            union { u16 s[16]; uint4 v[2]; } uh;
#pragma unroll
            for (int k = 0; k < 16; ++k) uh.s[k] = f2h(tile[c0 + k][nrow]);
            size_t oidx = ((size_t)(b * NN + nb + nrow)) * NC + cb + c0;
            *(uint4*)(ot + oidx)     = uh.v[0];
            *(uint4*)(ot + oidx + 8) = uh.v[1];
        }
    } else if (id < 2816) {
        int j = id - 2048;            // 0..767
        int m = j >> 8;               // tensor select
        int blk = j & 255;
        const float* src = (m == 0) ? Wq : (m == 1) ? Wk : Wv;
        u16* dst = (m == 0) ? wq : (m == 1) ? wk : wv;
        int i = (blk * 256 + t) * 4;
        float4 v = *(const float4*)(src + i);
        union { u16 s[4]; uint2 u2; } r;
        r.s[0] = f2h(v.x); r.s[1] = f2h(v.y); r.s[2] = f2h(v.z); r.s[3] = f2h(v.w);
        *(uint2*)(dst + i) = r.u2;
    } else {
        int idx = (id - 2816) * 256 + t;
        int dd = idx & 63;
        int i  = (idx >> 6) & 1023;
        int h  = idx >> 16;
        float f = relh[(h * 64 + dd) * 32 + (i & 31)] + relw[(h * 64 + dd) * 32 + (i >> 5)];
        ps[(h * 1024 + i) * 64 + dd] = f2h(f);
    }
}

// ================= kernel 2: projection GEMM, fp16, 2-phase DMA pipeline =================
// Double-buffered global_load_lds staging, ONE barrier per K-step: stage(k+1)
// issued BEFORE compute(k). This kernel is 8-wave LOCKSTEP (no second block's
// compute to hide the drain under), so prefetch genuinely helps here
// (round-5: ~-13us) -- unlike k_attn where cross-block TLP already hides it.
// q output is PRE-SCALED by log2(e) (softmax runs in exp2 domain).
__global__ __launch_bounds__(256) void k_proj(
    const u16* __restrict__ xt, const u16* __restrict__ dt,
    const u16* __restrict__ wq, const u16* __restrict__ wk, const u16* __restrict__ wv,
    const float* __restrict__ bq, const float* __restrict__ bk, const float* __restrict__ bv,
    u16* __restrict__ qt_o, u16* __restrict__ kt_o, u16* __restrict__ v_o) {
    __shared__ u16 Asm[2][128 * 32];   // UNPADDED: required by global_load_lds lane mapping
    __shared__ u16 Bsm[2][128 * 32];

    int p = blockIdx.z % 3;
    int b = blockIdx.z / 3;
    const u16 *Ap, *Bp;
    const float* bias;
    u16* Oq;
    if (p == 0)      { Ap = wq; Bp = xt; bias = bq; Oq = qt_o; }
    else if (p == 1) { Ap = wk; Bp = dt; bias = bk; Oq = kt_o; }
    else             { Ap = wv; Bp = dt; bias = bv; Oq = v_o; }
    Bp += (size_t)b * NN * NC;
    float oscale = (p == 0) ? LOG2E : 1.0f;

    int obase = blockIdx.x * 128;
    int nbase = blockIdx.y * 128;
    int t = threadIdx.x, wave = t >> 6, quad = (t & 63) >> 4, l15 = t & 15;
    int wr = (wave >> 1) * 64, wc = (wave & 1) * 64;

    f32x4 acc[4][4];
#pragma unroll
    for (int fo = 0; fo < 4; ++fo)
#pragma unroll
        for (int fn = 0; fn < 4; ++fn)
#pragma unroll
            for (int r = 0; r < 4; ++r) acc[fo][fn][r] = 0.f;

    auto stage = [&](int kk, int buf) {
#pragma unroll
        for (int u = 0; u < 2; ++u) {
            int c = u * 256 + t;
            int row = c >> 2, part = c & 3;
            __builtin_amdgcn_global_load_lds(
                (const __attribute__((address_space(1))) void*)(Ap + (size_t)(obase + row) * NC + kk + part * 8),
                (__attribute__((address_space(3))) void*)(&Asm[buf][0] + (size_t)(u * 256 + wave * 64) * 8), 16, 0, 0);
            __builtin_amdgcn_global_load_lds(
                (const __attribute__((address_space(1))) void*)(Bp + (size_t)(nbase + row) * NC + kk + part * 8),
                (__attribute__((address_space(3))) void*)(&Bsm[buf][0] + (size_t)(u * 256 + wave * 64) * 8), 16, 0, 0);
        }
    };

    stage(0, 0);
    __syncthreads();                 // vmcnt(0) drain + publish buf0

    for (int kk = 0; kk < NC; kk += 32) {
        int cur = (kk >> 5) & 1;
        if (kk + 32 < NC) stage(kk + 32, cur ^ 1);   // prefetch next K-step

        f16x8 af[4], bfr[4];
#pragma unroll
        for (int fo = 0; fo < 4; ++fo) af[fo] = *(const f16x8*)&Asm[cur][(wr + fo * 16 + l15) * 32 + quad * 8];
#pragma unroll
        for (int fn = 0; fn < 4; ++fn) bfr[fn] = *(const f16x8*)&Bsm[cur][(wc + fn * 16 + l15) * 32 + quad * 8];
#pragma unroll
        for (int fo = 0; fo < 4; ++fo)
#pragma unroll
            for (int fn = 0; fn < 4; ++fn)
                acc[fo][fn] = __builtin_amdgcn_mfma_f32_16x16x32_f16(af[fo], bfr[fn], acc[fo][fn], 0, 0, 0);

        __syncthreads();             // drains prefetch DMA (hidden by MFMAs) + guards overwrite
    }

#pragma unroll
    for (int fo = 0; fo < 4; ++fo) {
#pragma unroll
        for (int fn = 0; fn < 4; ++fn) {
            int o0 = obase + wr + fo * 16 + quad * 4;     // 4-aligned, never crosses a head
            int n = nbase + wc + fn * 16 + l15;
            if (p < 2) {
                union { u16 s[4]; uint2 v2; } uh;
#pragma unroll
                for (int r = 0; r < 4; ++r) uh.s[r] = f2h((acc[fo][fn][r] + bias[o0 + r]) * oscale);
                int head = o0 >> 6, dd0 = o0 & 63;
                size_t idx = (((size_t)(b * NHD + head) * NN) + n) * DH + dd0;
                *(uint2*)&Oq[idx] = uh.v2;
            } else {
#pragma unroll
                for (int r = 0; r < 4; ++r) {
                    int o = o0 + r;
                    int head = o >> 6, dd = o & 63;
                    Oq[((size_t)(b * NHD + head) * DH + dd) * NN + n] = f2h(acc[fo][fn][r] + bias[o]);
                }
            }
        }
    }
}

// ================= kernel 3: fused flash attention v9 =================
// v9 = v6 skeleton (best measured: KVBLK=128, dedicated stage phase, 48KB,
// 2 blocks/CU) + half-interleaved softmax/PV: after the (mandatory) global
// max + defer-check, each 64-j half runs {exp2 -> cvt_pk -> lsum via
// v_dot2_f32_f16 on packed pairs -> permlane -> PV}. Half B's exp2 VALU can
// issue while half A's PV MFMAs drain (no barrier between; MFMA pipe is
// non-blocking after issue) -- v6 serialized ALL softmax before ALL PV.
// lsum now sums the same fp16-rounded P that PV consumes (consistent).
// XOR chunk swizzle, in-register P transpose, defer-max (T13), setprio (T5).
__global__ __launch_bounds__(256, 2) void k_attn(
    const u16* __restrict__ qt, const u16* __restrict__ kt,
    const u16* __restrict__ v_, const u16* __restrict__ pos,
    float* __restrict__ out) {
    __shared__ u16 Bs[128 * 128];      // rows j: chunks 0-7 = K[j], 8-15 = Q[j] (swizzled)
    __shared__ u16 Vt[64 * 128];       // [d][j 128] (swizzled)

    // XCD swizzle: all 8 i-blocks of group g=(b,head) land on XCD g%8
    int n = blockIdx.x;
    int g = n & 63;
    int ib = n >> 6;
    int head = g & 7, b = g >> 3;

    int t = threadIdx.x, ws = t >> 6, lane = t & 63, h = lane >> 5, l31 = lane & 31;
    size_t bh = (size_t)(b * NHD + head);
    const u16* qb = qt + bh * NN * DH;
    const u16* kb = kt + bh * NN * DH;
    const u16* vb = v_ + bh * DH * NN;
    const u16* pb = pos + (size_t)head * NN * DH;
    int i0 = ib * 128;
    int iglob = i0 + ws * 32 + l31;

    // wave-private B-operand frags: k 0..63 = q_i (pre-scaled by log2e), 64..127 = pos_i
    f16x8 qf[8];
#pragma unroll
    for (int ks = 0; ks < 4; ++ks) qf[ks] = *(const f16x8*)&qb[(size_t)iglob * DH + ks * 16 + h * 8];
#pragma unroll
    for (int ks = 4; ks < 8; ++ks) qf[ks] = *(const f16x8*)&pb[(size_t)iglob * DH + (ks - 4) * 16 + h * 8];

    f32x16 oacc[2];
#pragma unroll
    for (int df = 0; df < 2; ++df)
#pragma unroll
        for (int r = 0; r < 16; ++r) oacc[df][r] = 0.f;
    float m_ = -__builtin_inff(), l_ = 0.f;
    int swz = l31 & 7;                 // read-side XOR key (row & 7)
    const hf16x2 kone = {(__fp16)1.0f, (__fp16)1.0f};

    for (int jc = 0; jc < NN; jc += 128) {
        __syncthreads();
        // ---- stage Bs via DMA: 2048 chunks of 16B; lane's LDS slot is linear,
        // source chunk is XOR-permuted so LDS[row][p] holds logical chunk p^(row&7)
#pragma unroll
        for (int u = 0; u < 8; ++u) {
            int c = u * 256 + t;
            int row = c >> 4, c16 = c & 15;
            int gch = c16 ^ (row & 7);
            const u16* src = (gch < 8) ? &kb[(size_t)(jc + row) * DH + gch * 8]
                                       : &qb[(size_t)(jc + row) * DH + (gch - 8) * 8];
            __builtin_amdgcn_global_load_lds(
                (const __attribute__((address_space(1))) void*)src,
                (__attribute__((address_space(3))) void*)(Bs + (u * 256 + ws * 64) * 8), 16, 0, 0);
        }
        // ---- stage Vt via DMA: 1024 chunks
#pragma unroll
        for (int u = 0; u < 4; ++u) {
            int c = u * 256 + t;
            int row = c >> 4, c16 = c & 15;
            int gch = c16 ^ (row & 7);
            __builtin_amdgcn_global_load_lds(
                (const __attribute__((address_space(1))) void*)&vb[(size_t)row * NN + jc + gch * 8],
                (__attribute__((address_space(3))) void*)(Vt + (u * 256 + ws * 64) * 8), 16, 0, 0);
        }
        __syncthreads();

        // ---- S^T: 4 j-frags of 32 rows, extended K=128 over 8 ks ----
        f32x16 sacc[4];
#pragma unroll
        for (int jf = 0; jf < 4; ++jf)
#pragma unroll
            for (int r = 0; r < 16; ++r) sacc[jf][r] = 0.f;
        __builtin_amdgcn_s_setprio(1);
#pragma unroll
        for (int jf = 0; jf < 4; ++jf)
#pragma unroll
            for (int ks = 0; ks < 8; ++ks) {
                f16x8 af = *(const f16x8*)&Bs[(jf * 32 + l31) * 128 + ((ks * 2 + h) ^ swz) * 8];
                sacc[jf] = __builtin_amdgcn_mfma_f32_32x32x16_f16(af, qf[ks], sacc[jf], 0, 0, 0);
            }
        __builtin_amdgcn_s_setprio(0);

        // ---- global max over 128 j (required before any exp: boundedness) ----
        float mj[4];
#pragma unroll
        for (int jf = 0; jf < 4; ++jf) {
            float a = fmaxf(fmaxf(sacc[jf][0], sacc[jf][1]), sacc[jf][2]);
            a = fmaxf(fmaxf(a, sacc[jf][3]), sacc[jf][4]);
            a = fmaxf(fmaxf(a, sacc[jf][5]), sacc[jf][6]);
            a = fmaxf(fmaxf(a, sacc[jf][7]), sacc[jf][8]);
            a = fmaxf(fmaxf(a, sacc[jf][9]), sacc[jf][10]);
            a = fmaxf(fmaxf(a, sacc[jf][11]), sacc[jf][12]);
            a = fmaxf(fmaxf(a, sacc[jf][13]), sacc[jf][14]);
            mj[jf] = fmaxf(a, sacc[jf][15]);
        }
        float mloc = fmaxf(fmaxf(mj[0], mj[1]), fmaxf(mj[2], mj[3]));
        mloc = fmaxf(mloc, __shfl_xor(mloc, 32));
        // defer-max (T13): rescale only when running max grew by >8 (exp2
        // domain => P bounded by 2^8=256, safely inside fp16; fp32 accum).
        if (__any(mloc - m_ > 8.f)) {
            float mnew = fmaxf(m_, mloc);
            float alpha = __builtin_amdgcn_exp2f(m_ - mnew);
            m_ = mnew;
#pragma unroll
            for (int df = 0; df < 2; ++df)
#pragma unroll
                for (int r = 0; r < 16; ++r) oacc[df][r] *= alpha;
            l_ *= alpha;
        }

        // ---- half-interleaved softmax finish + PV ----
        // Per 64-j half: exp2 -> cvt_pk -> lsum (fdot2 on packed) -> permlane
        // -> PV. Half B's exp2 overlaps half A's in-flight PV MFMAs.
        // P layout: lane(h,l31) holds sacc[jf][r] = P[j5=(r&3)+8*(r>>2)+4h][i=l31].
        // PV B-frag for slice jw needs pf[e] = P[jw*16+h*8+e][l31]; with
        // r0=(jw&1)*8: h=0 needs {own a0,a1 | h=1's a0,a1}; h=1 needs
        // {h=0's b0,b1 | own b0,b1}; permlane32_swap(a,b) -> {w0, w2}.
        float lsum = 0.f;
#pragma unroll
        for (int half = 0; half < 2; ++half) {
#pragma unroll
            for (int jf = half * 2; jf < half * 2 + 2; ++jf)
#pragma unroll
                for (int r = 0; r < 16; ++r)
                    sacc[jf][r] = __builtin_amdgcn_exp2f(sacc[jf][r] - m_);
            __builtin_amdgcn_s_setprio(1);
#pragma unroll
            for (int jw = half * 4; jw < half * 4 + 4; ++jw) {
                int jf = jw >> 1, r0 = (jw & 1) * 8;
                union { hf16x2 v; unsigned u; } a0, a1, b0, b1;
                a0.v = __builtin_amdgcn_cvt_pkrtz(sacc[jf][r0 + 0], sacc[jf][r0 + 1]);
                a1.v = __builtin_amdgcn_cvt_pkrtz(sacc[jf][r0 + 2], sacc[jf][r0 + 3]);
                b0.v = __builtin_amdgcn_cvt_pkrtz(sacc[jf][r0 + 4], sacc[jf][r0 + 5]);
                b1.v = __builtin_amdgcn_cvt_pkrtz(sacc[jf][r0 + 6], sacc[jf][r0 + 7]);
                lsum = __builtin_amdgcn_fdot2(a0.v, kone, lsum, false);
                lsum = __builtin_amdgcn_fdot2(a1.v, kone, lsum, false);
                lsum = __builtin_amdgcn_fdot2(b0.v, kone, lsum, false);
                lsum = __builtin_amdgcn_fdot2(b1.v, kone, lsum, false);
                uint2v s0 = __builtin_amdgcn_permlane32_swap(a0.u, b0.u, false, false);
                uint2v s1 = __builtin_amdgcn_permlane32_swap(a1.u, b1.u, false, false);
                union { unsigned w[4]; f16x8 f; } pf;
                pf.w[0] = s0.x;
                pf.w[1] = s1.x;
                pf.w[2] = s0.y;
                pf.w[3] = s1.y;
#pragma unroll
                for (int df = 0; df < 2; ++df) {
                    f16x8 vf = *(const f16x8*)&Vt[(df * 32 + l31) * 128 + ((jw * 2 + h) ^ swz) * 8];
                    oacc[df] = __builtin_amdgcn_mfma_f32_32x32x16_f16(vf, pf.f, oacc[df], 0, 0, 0);
                }
            }
            __builtin_amdgcn_s_setprio(0);
        }
        lsum += __shfl_xor(lsum, 32);
        l_ += lsum;
    }

    // ---- epilogue ----
    float li = 1.0f / l_;
#pragma unroll
    for (int df = 0; df < 2; ++df)
#pragma unroll
        for (int r = 0; r < 16; ++r) {
            int dd = df * 32 + (r & 3) + 8 * (r >> 2) + 4 * h;
            out[((size_t)(b * NC) + head * DH + dd) * NN + i0 + ws * 32 + l31] = oacc[df][r] * li;
        }
}

// ================= workspace layout (bytes) =================
#define SXT  (8u * 1024u * 512u * 2u)      /* 8 MB: [B,N,C] fp16 */
#define SW   (512u * 512u * 2u)
#define SQT  SXT
#define SPOS (8u * 1024u * 64u * 2u)

#define OFF_XT   (0u)
#define OFF_DT   (OFF_XT + SXT)
#define OFF_WQ   (OFF_DT + SXT)
#define OFF_WK   (OFF_WQ + SW)
#define OFF_WV   (OFF_WK + SW)
#define OFF_QT   (OFF_WV + SW)
#define OFF_KT   (OFF_QT + SQT)
#define OFF_V    (OFF_KT + SQT)
#define OFF_POS  (OFF_V + SQT)
// total = 5*8388608 + 3*524288 + 1048576 = 44,564,480 bytes (~42.5 MiB)

extern "C" void kernel_launch(void* const* d_in, const int* in_sizes, int n_in,
                              void* d_out, int out_size, void* d_ws, size_t ws_size,
                              hipStream_t stream) {
    const float* x   = (const float*)d_in[0];
    const float* d   = (const float*)d_in[1];
    const float* Wq  = (const float*)d_in[2];
    const float* bq  = (const float*)d_in[3];
    const float* Wk  = (const float*)d_in[4];
    const float* bk  = (const float*)d_in[5];
    const float* Wv  = (const float*)d_in[6];
    const float* bv  = (const float*)d_in[7];
    const float* rh  = (const float*)d_in[8];
    const float* rw  = (const float*)d_in[9];

    char* ws = (char*)d_ws;
    u16* xt = (u16*)(ws + OFF_XT);
    u16* dt = (u16*)(ws + OFF_DT);
    u16* wq = (u16*)(ws + OFF_WQ);
    u16* wk = (u16*)(ws + OFF_WK);
    u16* wv = (u16*)(ws + OFF_WV);
    u16* qt = (u16*)(ws + OFF_QT);
    u16* kt = (u16*)(ws + OFF_KT);
    u16* v_ = (u16*)(ws + OFF_V);
    u16* ps = (u16*)(ws + OFF_POS);

    k_prep<<<4864, 256, 0, stream>>>(x, d, Wq, Wk, Wv, rh, rw, xt, dt, wq, wk, wv, ps);
    k_proj<<<dim3(4, 8, 24), 256, 0, stream>>>(xt, dt, wq, wk, wv, bq, bk, bv, qt, kt, v_);
    k_attn<<<512, 256, 0, stream>>>(qt, kt, v_, ps, (float*)d_out);
}